// Round 5
// baseline (258.004 us; speedup 1.0000x reference)
//
#include <hip/hip_runtime.h>
#include <float.h>
#include <limits.h>
#include <math.h>

// ClusterLayer: B=131072 rows, K=1024 clusters, D=128.
// out (float32): [0] inertia/B, [1] xe/K, [2..2+B) cl as float.
//
// R5: 1-pass RNE-bf16 MFMA distances + top-3 tracking; near-ties resolved by
// a tiered exact-f64 refine (2-candidate pair refine for gap2<TAU, full scan
// for gap3<TAU). Single barrier per K-tile, double-buffered B via
// global_load_lds.
//
// ws layout (bytes):
//   0      : double inertia_acc
//   8      : int    cnt2   (pair-flagged rows)
//   12     : int    cnt3   (full-flagged rows)
//   16     : float  w2[1024]
//   4608   : short  wh[131072]      (256 KB, bf16-RNE W in tile fragment order)
//   266752 : int    pair2[3*24576]  (288 KB)
//   561664 : int    full3[8192]     (32 KB)  -> end 594432

#define TAU 0.012f

using bf16x8 = __attribute__((ext_vector_type(8))) short;
using f32x4  = __attribute__((ext_vector_type(4))) float;
using s16x4  = __attribute__((ext_vector_type(4))) short;

static __device__ __forceinline__ short f2bf_rne(float f) {
    unsigned u = __float_as_uint(f);
    return (short)((u + 0x7FFFu + ((u >> 16) & 1u)) >> 16);
}
static __device__ __forceinline__ short f2bf_trunc(float f) {
    return (short)(__float_as_uint(f) >> 16);
}
static __device__ __forceinline__ float bf2f(short h) {
    return __uint_as_float(((unsigned int)(unsigned short)h) << 16);
}
static __device__ __forceinline__ bool lexlt(float v1, int i1, float v2, int i2) {
    return v1 < v2 || (v1 == v2 && i1 < i2);
}
static __device__ __forceinline__ void gload_lds16(const void* g, void* l) {
    __builtin_amdgcn_global_load_lds(
        (const __attribute__((address_space(1))) unsigned int*)g,
        (__attribute__((address_space(3))) unsigned int*)l, 16, 0, 0);
}
#define FENCE() do { asm volatile("" ::: "memory"); __builtin_amdgcn_sched_barrier(0); } while (0)

// W prep: w2 per cluster (f32-exact) + bf16-RNE hi image in 64-col-tile
// fragment order: shorts: tile*8192 + (c>>4)*2048 + (d>>5)*512
//                 + ((d>>3)&3)*128 + (c&15)*8 + (d&7);  tile=k>>6, c=k&63
__global__ void wprep_kernel(const float* __restrict__ W, float* __restrict__ w2,
                             short* __restrict__ wh, int write_wh)
{
    const int k = blockIdx.x;
    const int d = threadIdx.x;     // 0..127
    float v = W[(size_t)k * 128 + d];
    float sq = v * v;
    for (int off = 1; off < 64; off <<= 1) sq += __shfl_xor(sq, off, 64);
    __shared__ float p[2];
    if ((d & 63) == 0) p[d >> 6] = sq;
    __syncthreads();
    if (d == 0) w2[k] = p[0] + p[1];
    if (write_wh) {
        const int tile = k >> 6, c = k & 63;
        size_t base = (size_t)tile * 8192 + (size_t)(c >> 4) * 2048 + (size_t)(d >> 5) * 512
                    + (size_t)((d >> 3) & 3) * 128 + (size_t)(c & 15) * 8 + (size_t)(d & 7);
        wh[base] = f2bf_rne(v);
    }
}

// LDS (bytes): lB0 0..16384 | lB1 16384..32768 | lw2 32768..36864 |
//              mscr 36864..39424 (128 rows x 5 ints) | dred 39424..39552
__global__ __launch_bounds__(512, 4)
void dist_argmin_1p(const float* __restrict__ X, const short* __restrict__ wh,
                    const float* __restrict__ w2g, float* __restrict__ cl_out,
                    double* __restrict__ inertia_acc,
                    int* __restrict__ cnt2, int* __restrict__ cnt3,
                    int* __restrict__ pair2, int cap2,
                    int* __restrict__ full3, int cap3)
{
    __shared__ __align__(16) char smem[39552];
    char*   lB0  = smem;
    char*   lB1  = smem + 16384;
    float*  lw2  = (float*)(smem + 32768);
    int*    mscr = (int*)(smem + 36864);
    double* dred = (double*)(smem + 39424);

    const int tid    = threadIdx.x;
    const int lane   = tid & 63;
    const int laneLo = lane & 15;
    const int laneHi = lane >> 4;
    const int wid    = tid >> 6;
    const int rowg   = wid >> 1;
    const int colg   = wid & 1;
    const int rowbase = blockIdx.x * 128;

    // w2 -> LDS
    lw2[tid]       = w2g[tid];
    lw2[tid + 512] = w2g[tid + 512];

    // ---- A (hi only, RNE) straight from global into registers + ||x||^2 ----
    bf16x8 ah[2][4];
    float  x2r[2];
    #pragma unroll
    for (int m = 0; m < 2; ++m) {
        const float* xp = X + (size_t)(rowbase + rowg * 32 + m * 16 + laneLo) * 128 + laneHi * 8;
        float s = 0.f;
        #pragma unroll
        for (int k0b = 0; k0b < 4; ++k0b) {
            float4 v0 = *reinterpret_cast<const float4*>(xp + k0b * 32);
            float4 v1 = *reinterpret_cast<const float4*>(xp + k0b * 32 + 4);
            float fv[8] = {v0.x, v0.y, v0.z, v0.w, v1.x, v1.y, v1.z, v1.w};
            bf16x8 hv;
            #pragma unroll
            for (int u = 0; u < 8; ++u) {
                s = fmaf(fv[u], fv[u], s);
                hv[u] = f2bf_rne(fv[u]);
            }
            ah[m][k0b] = hv;
        }
        s += __shfl_xor(s, 16, 64);
        s += __shfl_xor(s, 32, 64);
        x2r[m] = s;                       // every lane: x2 of row_low = laneLo
    }
    asm volatile("s_waitcnt lgkmcnt(0)" ::: "memory");   // lw2 ds_writes drained
    __builtin_amdgcn_sched_barrier(0);

    // ---- issue B[0] -> lB0 (16 KB; wave wid copies 2 KB) ----
    const char* whb = (const char*)wh;
    #pragma unroll
    for (int q = 0; q < 2; ++q)
        gload_lds16(whb + wid * 2048 + q * 1024 + lane * 16,
                    lB0 + wid * 2048 + q * 1024);

    float t1v[2][4], t2v[2][4], t3v[2][4];
    int   t1i[2][4], t2i[2][4];
    #pragma unroll
    for (int m = 0; m < 2; ++m)
        #pragma unroll
        for (int r = 0; r < 4; ++r) {
            t1v[m][r] = FLT_MAX; t2v[m][r] = FLT_MAX; t3v[m][r] = FLT_MAX;
            t1i[m][r] = INT_MAX; t2i[m][r] = INT_MAX;
        }

    const char* pB0 = lB0 + colg * 8192 + lane * 16;
    const char* pB1 = lB1 + colg * 8192 + lane * 16;

    auto compute = [&](int t, const char* pBb) {
        float w2v[2];
        #pragma unroll
        for (int nt = 0; nt < 2; ++nt)
            w2v[nt] = lw2[t * 64 + colg * 32 + nt * 16 + laneLo];

        f32x4 acc[2][2];
        __builtin_amdgcn_s_setprio(1);
        #pragma unroll
        for (int nt = 0; nt < 2; ++nt) {
            f32x4 a0 = (f32x4){0.f, 0.f, 0.f, 0.f};
            f32x4 a1 = (f32x4){0.f, 0.f, 0.f, 0.f};
            #pragma unroll
            for (int k0b = 0; k0b < 4; ++k0b) {
                bf16x8 bh = *reinterpret_cast<const bf16x8*>(pBb + nt * 4096 + k0b * 1024);
                a0 = __builtin_amdgcn_mfma_f32_16x16x32_bf16(ah[0][k0b], bh, a0, 0, 0, 0);
                a1 = __builtin_amdgcn_mfma_f32_16x16x32_bf16(ah[1][k0b], bh, a1, 0, 0, 0);
            }
            acc[nt][0] = a0; acc[nt][1] = a1;
        }
        __builtin_amdgcn_s_setprio(0);

        // dist = w2 - 2*dot_hi; branch-free top-3 (values) + top-2 indices.
        // strict < with ascending col order => first-occurrence argmin.
        #pragma unroll
        for (int nt = 0; nt < 2; ++nt) {
            const int col = t * 64 + colg * 32 + nt * 16 + laneLo;
            #pragma unroll
            for (int m = 0; m < 2; ++m)
                #pragma unroll
                for (int r = 0; r < 4; ++r) {
                    float dv = fmaf(-2.f, acc[nt][m][r], w2v[nt]);
                    bool c1 = dv < t1v[m][r];
                    bool c2 = dv < t2v[m][r];
                    t3v[m][r] = fminf(t3v[m][r], fmaxf(t2v[m][r], dv));
                    t2v[m][r] = fminf(t2v[m][r], fmaxf(t1v[m][r], dv));
                    t2i[m][r] = c1 ? t1i[m][r] : (c2 ? col : t2i[m][r]);
                    t1i[m][r] = c1 ? col : t1i[m][r];
                    t1v[m][r] = fminf(t1v[m][r], dv);
                }
        }
    };

    #pragma unroll 1
    for (int t = 0; t < 15; ++t) {
        asm volatile("s_waitcnt vmcnt(0)" ::: "memory");   // my B[t] DMA landed
        __builtin_amdgcn_sched_barrier(0);
        __builtin_amdgcn_s_barrier();                      // everyone's landed; prev readers done
        FENCE();
        // stage B[t+1] into the other buffer
        {
            const char* src = whb + (size_t)(t + 1) * 16384;
            char* dst = ((t + 1) & 1) ? lB1 : lB0;
            #pragma unroll
            for (int q = 0; q < 2; ++q)
                gload_lds16(src + wid * 2048 + q * 1024 + lane * 16,
                            dst + wid * 2048 + q * 1024);
        }
        compute(t, (t & 1) ? pB1 : pB0);
    }
    asm volatile("s_waitcnt vmcnt(0)" ::: "memory");
    __builtin_amdgcn_sched_barrier(0);
    __builtin_amdgcn_s_barrier();
    FENCE();
    compute(15, pB1);

    // ---- merge top-3 across the 16 col-lanes of each row ----
    #pragma unroll
    for (int off = 1; off < 16; off <<= 1) {
        #pragma unroll
        for (int m = 0; m < 2; ++m)
            #pragma unroll
            for (int r = 0; r < 4; ++r) {
                float ov1 = __shfl_xor(t1v[m][r], off, 64);
                int   oi1 = __shfl_xor(t1i[m][r], off, 64);
                float ov2 = __shfl_xor(t2v[m][r], off, 64);
                int   oi2 = __shfl_xor(t2i[m][r], off, 64);
                float ov3 = __shfl_xor(t3v[m][r], off, 64);
                // insert ov1
                if (lexlt(ov1, oi1, t1v[m][r], t1i[m][r])) {
                    t3v[m][r] = t2v[m][r];
                    t2v[m][r] = t1v[m][r]; t2i[m][r] = t1i[m][r];
                    t1v[m][r] = ov1;       t1i[m][r] = oi1;
                } else if (lexlt(ov1, oi1, t2v[m][r], t2i[m][r])) {
                    t3v[m][r] = t2v[m][r];
                    t2v[m][r] = ov1; t2i[m][r] = oi1;
                } else if (ov1 < t3v[m][r]) {
                    t3v[m][r] = ov1;
                }
                // insert ov2 (>= ov1, can never claim slot 1)
                if (lexlt(ov2, oi2, t2v[m][r], t2i[m][r])) {
                    t3v[m][r] = t2v[m][r];
                    t2v[m][r] = ov2; t2i[m][r] = oi2;
                } else if (ov2 < t3v[m][r]) {
                    t3v[m][r] = ov2;
                }
                // insert ov3 (value only)
                t3v[m][r] = fminf(t3v[m][r], ov3);
            }
    }

    // x2 for reported rows (uniform shfl for all lanes)
    float x2v[2][4];
    #pragma unroll
    for (int m = 0; m < 2; ++m)
        #pragma unroll
        for (int r = 0; r < 4; ++r)
            x2v[m][r] = __shfl(x2r[m], laneHi * 4 + r, 64);

    // ---- merge col-halves via LDS ----
    __syncthreads();
    if (colg == 1 && laneLo == 0) {
        #pragma unroll
        for (int m = 0; m < 2; ++m)
            #pragma unroll
            for (int r = 0; r < 4; ++r) {
                const int row = rowg * 32 + m * 16 + laneHi * 4 + r;
                mscr[row * 5 + 0] = __float_as_int(t1v[m][r]);
                mscr[row * 5 + 1] = t1i[m][r];
                mscr[row * 5 + 2] = __float_as_int(t2v[m][r]);
                mscr[row * 5 + 3] = t2i[m][r];
                mscr[row * 5 + 4] = __float_as_int(t3v[m][r]);
            }
    }
    __syncthreads();
    double local = 0.0;
    if (colg == 0 && laneLo == 0) {
        #pragma unroll
        for (int m = 0; m < 2; ++m)
            #pragma unroll
            for (int r = 0; r < 4; ++r) {
                const int row = rowg * 32 + m * 16 + laneHi * 4 + r;
                float ov1 = __int_as_float(mscr[row * 5 + 0]);
                int   oi1 = mscr[row * 5 + 1];
                float ov2 = __int_as_float(mscr[row * 5 + 2]);
                int   oi2 = mscr[row * 5 + 3];
                float ov3 = __int_as_float(mscr[row * 5 + 4]);
                float b1v = t1v[m][r], b2v = t2v[m][r], b3v = t3v[m][r];
                int   b1i = t1i[m][r], b2i = t2i[m][r];
                if (lexlt(ov1, oi1, b1v, b1i)) {
                    b3v = b2v; b2v = b1v; b2i = b1i; b1v = ov1; b1i = oi1;
                } else if (lexlt(ov1, oi1, b2v, b2i)) {
                    b3v = b2v; b2v = ov1; b2i = oi1;
                } else if (ov1 < b3v) b3v = ov1;
                if (lexlt(ov2, oi2, b2v, b2i)) {
                    b3v = b2v; b2v = ov2; b2i = oi2;
                } else if (ov2 < b3v) b3v = ov2;
                b3v = fminf(b3v, ov3);

                const int grow = rowbase + row;
                if (b3v - b1v < TAU) {                 // >=3 contenders: full refine
                    int slot = atomicAdd(cnt3, 1);
                    if (slot < cap3) {
                        full3[slot] = grow;
                    } else {
                        cl_out[grow] = (float)b1i;
                        local += (double)(b1v + x2v[m][r]);
                    }
                } else if (b2v - b1v < TAU) {          // exactly 2: pair refine
                    int slot = atomicAdd(cnt2, 1);
                    if (slot < cap2) {
                        pair2[slot * 3 + 0] = grow;
                        pair2[slot * 3 + 1] = b1i;
                        pair2[slot * 3 + 2] = b2i;
                    } else {
                        cl_out[grow] = (float)b1i;
                        local += (double)(b1v + x2v[m][r]);
                    }
                } else {
                    cl_out[grow] = (float)b1i;
                    local += (double)(b1v + x2v[m][r]);
                }
            }
        dred[rowg * 4 + laneHi] = local;
    }
    __syncthreads();
    if (tid == 0) {
        double tt = 0.0;
        for (int i = 0; i < 16; ++i) tt += dred[i];
        atomicAdd(inertia_acc, tt);
    }
}

// exact f64 decision between 2 candidate clusters (one thread per row)
__global__ void pair_refine(const float* __restrict__ X, const float* __restrict__ W,
                            const int* __restrict__ cnt2, const int* __restrict__ pair2,
                            int cap2, float* __restrict__ cl_out,
                            double* __restrict__ inertia_acc)
{
    int n = *cnt2; if (n > cap2) n = cap2;
    int idx = blockIdx.x * 256 + threadIdx.x;
    if (idx >= n) return;
    int row = pair2[idx * 3 + 0];
    int i1  = pair2[idx * 3 + 1];
    int i2  = pair2[idx * 3 + 2];
    const float* xr = X + (size_t)row * 128;
    const float* wa = W + (size_t)i1 * 128;
    const float* wb = W + (size_t)i2 * 128;
    double d1 = 0.0, d2 = 0.0;
    #pragma unroll 8
    for (int d = 0; d < 128; ++d) {
        double xv = (double)xr[d];
        double e1 = xv - (double)wa[d]; d1 = fma(e1, e1, d1);
        double e2 = xv - (double)wb[d]; d2 = fma(e2, e2, d2);
    }
    int win; double dw;
    if (d1 < d2 || (d1 == d2 && i1 < i2)) { win = i1; dw = d1; }
    else                                  { win = i2; dw = d2; }
    cl_out[row] = (float)win;
    atomicAdd(inertia_acc, dw);
}

// exact f64 argmin over all 1024 clusters for full-flagged rows
__global__ void full_refine(const float* __restrict__ X, const float* __restrict__ W,
                            const int* __restrict__ cnt3, const int* __restrict__ full3,
                            int cap3, float* __restrict__ cl_out,
                            double* __restrict__ inertia_acc)
{
    __shared__ double sv[4];
    __shared__ int    si[4];
    __shared__ float  xrow[128];
    int n = *cnt3;
    if (n > cap3) n = cap3;
    const int tid = threadIdx.x;

    for (int f = blockIdx.x; f < n; f += gridDim.x) {
        int row = full3[f];
        if (tid < 128) xrow[tid] = X[(size_t)row * 128 + tid];
        __syncthreads();

        double best = DBL_MAX; int bi = INT_MAX;
        for (int cc = 0; cc < 4; ++cc) {
            int c = tid + 256 * cc;
            double dot = 0.0, wsq = 0.0;
            for (int d = 0; d < 128; ++d) {
                double wv = (double)W[(size_t)c * 128 + d];
                dot = fma((double)xrow[d], wv, dot);
                wsq = fma(wv, wv, wsq);
            }
            double dist = wsq - 2.0 * dot;
            if (dist < best || (dist == best && c < bi)) { best = dist; bi = c; }
        }
        for (int off = 1; off < 64; off <<= 1) {
            double ov = __shfl_xor(best, off, 64);
            int    oi = __shfl_xor(bi, off, 64);
            if (ov < best || (ov == best && oi < bi)) { best = ov; bi = oi; }
        }
        if ((tid & 63) == 0) { sv[tid >> 6] = best; si[tid >> 6] = bi; }
        __syncthreads();
        if (tid == 0) {
            for (int wv = 1; wv < 4; ++wv)
                if (sv[wv] < best || (sv[wv] == best && si[wv] < bi)) { best = sv[wv]; bi = si[wv]; }
            double x2 = 0.0;
            for (int d = 0; d < 128; ++d) { double xv = (double)xrow[d]; x2 = fma(xv, xv, x2); }
            cl_out[row] = (float)bi;
            atomicAdd(inertia_acc, x2 + best);
        }
        __syncthreads();
    }
}

// ---------------- fallback (3-pass in-kernel conversion, ws too small) ------
__global__ __launch_bounds__(512, 1)
void dist_argmin_v2(const float* __restrict__ X, const float* __restrict__ W,
                    const float* __restrict__ w2g, float* __restrict__ cl_out,
                    double* __restrict__ inertia_acc,
                    int* __restrict__ flag_cnt, int* __restrict__ flag_rows,
                    int flag_cap)
{
    __shared__ __align__(16) char smem[133760];
    short*  Areg = (short*)smem;
    short*  Breg = (short*)(smem + 65536);
    int*    mscr = (int*)(smem + 131072);
    float*  lx2  = (float*)(smem + 131072 + 2048);
    double* dred = (double*)(smem + 131072 + 2048 + 512);

    const int tid    = threadIdx.x;
    const int lane   = tid & 63;
    const int laneLo = lane & 15;
    const int laneHi = lane >> 4;
    const int wid    = tid >> 6;
    const int rowg   = wid >> 1;
    const int colg   = wid & 1;
    const int rowbase = blockIdx.x * 128;

    {
        const int r = tid >> 2, q = tid & 3;
        float s = 0.f;
        #pragma unroll
        for (int j = 0; j < 8; ++j) {
            const int d0 = q * 4 + j * 16;
            float4 v = *reinterpret_cast<const float4*>(X + (size_t)(rowbase + r) * 128 + d0);
            float fv[4] = {v.x, v.y, v.z, v.w};
            s16x4 hv, lv;
            #pragma unroll
            for (int u = 0; u < 4; ++u) {
                s = fmaf(fv[u], fv[u], s);
                short h = f2bf_trunc(fv[u]);
                short l = f2bf_trunc(fv[u] - bf2f(h));
                hv[u] = h; lv[u] = l;
            }
            const int kb = d0 >> 3, off = d0 & 7;
            short* pa = Areg + (kb * 128 + r) * 8 + off;
            *reinterpret_cast<s16x4*>(pa)         = hv;
            *reinterpret_cast<s16x4*>(pa + 16384) = lv;
        }
        s += __shfl_xor(s, 1, 64);
        s += __shfl_xor(s, 2, 64);
        if (q == 0) lx2[r] = s;
    }

    float t1v[2][4], t2v[2][4];
    int   t1i[2][4];
    #pragma unroll
    for (int m = 0; m < 2; ++m)
        #pragma unroll
        for (int r = 0; r < 4; ++r) {
            t1v[m][r] = FLT_MAX; t2v[m][r] = FLT_MAX; t1i[m][r] = INT_MAX;
        }

    const char* pAbase = smem + laneHi * 2048 + (rowg * 32 + laneLo) * 16;
    const char* pBbase = smem + 65536 + colg * 16384 + lane * 16;

    for (int iter = 0; iter < 8; ++iter) {
        __syncthreads();
        {
            const int c = tid >> 2, q = tid & 3;
            const int nt = c >> 4, c15 = c & 15;
            #pragma unroll
            for (int j = 0; j < 8; ++j) {
                const int d0 = q * 4 + j * 16;
                float4 v = *reinterpret_cast<const float4*>(W + (size_t)(iter * 128 + c) * 128 + d0);
                float fv[4] = {v.x, v.y, v.z, v.w};
                s16x4 hv, lv;
                #pragma unroll
                for (int u = 0; u < 4; ++u) {
                    short h = f2bf_trunc(fv[u]);
                    short l = f2bf_trunc(fv[u] - bf2f(h));
                    hv[u] = h; lv[u] = l;
                }
                const int k0b = d0 >> 5, sub = (d0 >> 3) & 3, jj = d0 & 7;
                short* pb = Breg + ((nt * 4 + k0b) * 64 + sub * 16 + c15) * 8 + jj;
                *reinterpret_cast<s16x4*>(pb)         = hv;
                *reinterpret_cast<s16x4*>(pb + 16384) = lv;
            }
        }
        float w2v[4];
        #pragma unroll
        for (int nt = 0; nt < 4; ++nt)
            w2v[nt] = w2g[iter * 128 + colg * 64 + nt * 16 + laneLo];
        __syncthreads();

        f32x4 acc[2][4];
        #pragma unroll
        for (int m = 0; m < 2; ++m)
            #pragma unroll
            for (int nt = 0; nt < 4; ++nt)
                acc[m][nt] = (f32x4){0.f, 0.f, 0.f, 0.f};

        #pragma unroll
        for (int k0b = 0; k0b < 4; ++k0b) {
            bf16x8 ah[2], al[2];
            #pragma unroll
            for (int m = 0; m < 2; ++m) {
                ah[m] = *reinterpret_cast<const bf16x8*>(pAbase + k0b * 8192 + m * 256);
                al[m] = *reinterpret_cast<const bf16x8*>(pAbase + 32768 + k0b * 8192 + m * 256);
            }
            #pragma unroll
            for (int nt = 0; nt < 4; ++nt) {
                bf16x8 bh = *reinterpret_cast<const bf16x8*>(pBbase + nt * 4096 + k0b * 1024);
                bf16x8 bl = *reinterpret_cast<const bf16x8*>(pBbase + 32768 + nt * 4096 + k0b * 1024);
                #pragma unroll
                for (int m = 0; m < 2; ++m) {
                    acc[m][nt] = __builtin_amdgcn_mfma_f32_16x16x32_bf16(ah[m], bh, acc[m][nt], 0, 0, 0);
                    acc[m][nt] = __builtin_amdgcn_mfma_f32_16x16x32_bf16(ah[m], bl, acc[m][nt], 0, 0, 0);
                    acc[m][nt] = __builtin_amdgcn_mfma_f32_16x16x32_bf16(al[m], bh, acc[m][nt], 0, 0, 0);
                }
            }
        }

        #pragma unroll
        for (int nt = 0; nt < 4; ++nt) {
            const int col = iter * 128 + colg * 64 + nt * 16 + laneLo;
            #pragma unroll
            for (int m = 0; m < 2; ++m)
                #pragma unroll
                for (int r = 0; r < 4; ++r) {
                    float dv = fmaf(-2.f, acc[m][nt][r], w2v[nt]);
                    float hi = fmaxf(t1v[m][r], dv);
                    t2v[m][r] = fminf(t2v[m][r], hi);
                    bool cnd = dv < t1v[m][r];
                    t1i[m][r] = cnd ? col : t1i[m][r];
                    t1v[m][r] = fminf(t1v[m][r], dv);
                }
        }
    }

    #pragma unroll
    for (int off = 1; off < 16; off <<= 1) {
        #pragma unroll
        for (int m = 0; m < 2; ++m)
            #pragma unroll
            for (int r = 0; r < 4; ++r) {
                float ov1 = __shfl_xor(t1v[m][r], off, 64);
                int   oi1 = __shfl_xor(t1i[m][r], off, 64);
                float ov2 = __shfl_xor(t2v[m][r], off, 64);
                float nt2 = fminf(fminf(t2v[m][r], ov2), fmaxf(t1v[m][r], ov1));
                if (lexlt(ov1, oi1, t1v[m][r], t1i[m][r])) { t1v[m][r] = ov1; t1i[m][r] = oi1; }
                t2v[m][r] = nt2;
            }
    }

    __syncthreads();
    if (colg == 1 && laneLo == 0) {
        #pragma unroll
        for (int m = 0; m < 2; ++m)
            #pragma unroll
            for (int r = 0; r < 4; ++r) {
                const int row = rowg * 32 + m * 16 + laneHi * 4 + r;
                mscr[row * 4 + 0] = __float_as_int(t1v[m][r]);
                mscr[row * 4 + 1] = t1i[m][r];
                mscr[row * 4 + 2] = __float_as_int(t2v[m][r]);
            }
    }
    __syncthreads();
    double local = 0.0;
    if (colg == 0 && laneLo == 0) {
        #pragma unroll
        for (int m = 0; m < 2; ++m)
            #pragma unroll
            for (int r = 0; r < 4; ++r) {
                const int row = rowg * 32 + m * 16 + laneHi * 4 + r;
                float ov1 = __int_as_float(mscr[row * 4 + 0]);
                int   oi1 = mscr[row * 4 + 1];
                float ov2 = __int_as_float(mscr[row * 4 + 2]);
                float b1v = t1v[m][r], b2v;
                int   b1i = t1i[m][r];
                b2v = fminf(fminf(t2v[m][r], ov2), fmaxf(b1v, ov1));
                if (lexlt(ov1, oi1, b1v, b1i)) { b1v = ov1; b1i = oi1; }
                const int grow = rowbase + row;
                if (b2v - b1v < 1e-3f) {
                    int slot = atomicAdd(flag_cnt, 1);
                    if (slot < flag_cap) flag_rows[slot] = grow;
                    else { cl_out[grow] = (float)b1i; local += (double)(b1v + lx2[row]); }
                } else {
                    cl_out[grow] = (float)b1i;
                    local += (double)(b1v + lx2[row]);
                }
            }
        dred[rowg * 4 + laneHi] = local;
    }
    __syncthreads();
    if (tid == 0) {
        double t = 0.0;
        for (int i = 0; i < 16; ++i) t += dred[i];
        atomicAdd(inertia_acc, t);
    }
}

__global__ void finalize_kernel(const float* __restrict__ W, const float* __restrict__ w2,
                                const double* __restrict__ inertia, float* __restrict__ out)
{
    __shared__ float sh1[128], sh2[128];
    int d = threadIdx.x;                       // 128 threads
    float s = 0.f;
    for (int k = 0; k < 1024; ++k) s += W[(size_t)k * 128 + d];
    float t = 0.f;
    for (int j = 0; j < 8; ++j) t += w2[d + 128 * j];
    sh1[d] = s * s;
    sh2[d] = t;
    __syncthreads();
    for (int off = 64; off > 0; off >>= 1) {
        if (d < off) { sh1[d] += sh1[d + off]; sh2[d] += sh2[d + off]; }
        __syncthreads();
    }
    if (d == 0) {
        float xe = 2.f * sh2[0] - sh1[0];      // 2*trace(G) - sum(G)
        out[1] = xe / 1024.f;
        out[0] = (float)(*inertia / 131072.0);
    }
}

extern "C" void kernel_launch(void* const* d_in, const int* in_sizes, int n_in,
                              void* d_out, int out_size, void* d_ws, size_t ws_size,
                              hipStream_t stream)
{
    const float* X = (const float*)d_in[0];          // [131072,128] f32
    const float* W = (const float*)d_in[1];          // [1024,128]   f32
    float* out = (float*)d_out;                       // [131074]     f32
    char* ws = (char*)d_ws;

    double* inertia = (double*)ws;
    int*    cnt2    = (int*)(ws + 8);
    int*    cnt3    = (int*)(ws + 12);
    float*  w2      = (float*)(ws + 16);
    short*  wh      = (short*)(ws + 4608);
    int*    pair2   = (int*)(ws + 266752);
    int*    full3   = (int*)(ws + 561664);
    const int CAP2 = 24576, CAP3 = 8192;
    const size_t NEED = 594432;

    const bool precomp = ws_size >= NEED;

    hipMemsetAsync(ws, 0, 16, stream);               // inertia + cnt2 + cnt3

    if (precomp) {
        wprep_kernel<<<1024, 128, 0, stream>>>(W, w2, wh, 1);
        dist_argmin_1p<<<1024, 512, 0, stream>>>(X, wh, w2, out + 2, inertia,
                                                 cnt2, cnt3, pair2, CAP2, full3, CAP3);
        pair_refine<<<(CAP2 + 255) / 256, 256, 0, stream>>>(X, W, cnt2, pair2, CAP2,
                                                            out + 2, inertia);
        full_refine<<<256, 256, 0, stream>>>(X, W, cnt3, full3, CAP3, out + 2, inertia);
    } else {
        int* full3f = (int*)(ws + 4608);
        long cap = ((long)ws_size - 4608) / 4;
        int capf = cap < 0 ? 0 : (cap > 131072 ? 131072 : (int)cap);
        wprep_kernel<<<1024, 128, 0, stream>>>(W, w2, (short*)full3f, 0);
        dist_argmin_v2<<<1024, 512, 0, stream>>>(X, W, w2, out + 2, inertia,
                                                 cnt3, full3f, capf);
        full_refine<<<256, 256, 0, stream>>>(X, W, cnt3, full3f, capf, out + 2, inertia);
    }
    finalize_kernel<<<1, 128, 0, stream>>>(W, w2, inertia, out);
}